// Round 1
// baseline (1129.452 us; speedup 1.0000x reference)
//
#include <hip/hip_runtime.h>
#include <hip/hip_bf16.h>
#include <math.h>

#define KDIM 256   // feature dim for all GEMM K (and layer widths)

__device__ __forceinline__ float lrelu(float x, float s) { return x > 0.0f ? x : s * x; }

// ======================== CSR build ========================
__global__ void deg_kernel(const int* __restrict__ dst, int* __restrict__ deg, int E) {
  int e = blockIdx.x * blockDim.x + threadIdx.x;
  if (e < E) atomicAdd(&deg[dst[e]], 1);
}

__global__ __launch_bounds__(1024) void scan_kernel(const int* __restrict__ deg,
                                                    int* __restrict__ rowptr, int N) {
  __shared__ int sums[1024];
  int t = threadIdx.x;
  int CH = (N + 1023) / 1024;
  int base = t * CH;
  int s = 0;
  for (int i = 0; i < CH; ++i) { int idx = base + i; if (idx < N) s += deg[idx]; }
  sums[t] = s;
  __syncthreads();
  for (int off = 1; off < 1024; off <<= 1) {
    int v = (t >= off) ? sums[t - off] : 0;
    __syncthreads();
    sums[t] += v;
    __syncthreads();
  }
  int run = (t == 0) ? 0 : sums[t - 1];
  for (int i = 0; i < CH; ++i) {
    int idx = base + i;
    if (idx < N) { rowptr[idx] = run; run += deg[idx]; }
  }
  if (t == 1023) rowptr[N] = sums[1023];
}

__global__ void fill_kernel(const int* __restrict__ src, const int* __restrict__ dst,
                            int* __restrict__ cursor, int* __restrict__ colsrc, int E) {
  int e = blockIdx.x * blockDim.x + threadIdx.x;
  if (e < E) {
    int d = dst[e];
    int pos = atomicAdd(&cursor[d], 1);
    colsrc[pos] = src[e];
  }
}

// ======================== f32 tiled GEMM 128x128x16 ========================
// C = A @ B(^T).  A:[M,256] row-major.
// TRANS_B: B is [Ncols,256] (weight, we use its rows as output cols).
// else   : B is [256,Ncols].
// EPI_COS: Ncols==1024, block col-tile == one K-chunk of 128; computes
//          cosine-vs-mu epilogue directly into outcos[M,8]; C unused.
template<bool TRANS_B, bool EPI_COS>
__global__ __launch_bounds__(256) void gemm128(
    const float* __restrict__ A, const float* __restrict__ B,
    float* __restrict__ C,
    const float* __restrict__ mu, const float* __restrict__ norm_mu,
    float* __restrict__ outcos,
    int M, int Ncols)
{
  const int BK = 16;
  __shared__ float As[BK][128];
  __shared__ float Bs[BK][128];
  const int m0 = blockIdx.x * 128;
  const int n0 = blockIdx.y * 128;
  const int t  = threadIdx.x;
  const int tx = t & 15;        // col group (8 cols each)
  const int ty = t >> 4;        // row group (8 rows each)

  float acc[8][8];
  #pragma unroll
  for (int i = 0; i < 8; ++i)
    #pragma unroll
    for (int j = 0; j < 8; ++j) acc[i][j] = 0.0f;

  for (int kb = 0; kb < KDIM; kb += BK) {
    // ---- load A tile (transposed into As[k][m]) ----
    #pragma unroll
    for (int l = 0; l < 2; ++l) {
      int idx = t + l * 256;          // 0..511
      int r   = idx >> 2;             // 0..127
      int c4  = (idx & 3) << 2;       // 0,4,8,12
      int gr  = m0 + r;
      float4 v = make_float4(0.f, 0.f, 0.f, 0.f);
      if (gr < M) v = *(const float4*)&A[(size_t)gr * KDIM + kb + c4];
      As[c4 + 0][r] = v.x; As[c4 + 1][r] = v.y;
      As[c4 + 2][r] = v.z; As[c4 + 3][r] = v.w;
    }
    // ---- load B tile ----
    if (TRANS_B) {
      #pragma unroll
      for (int l = 0; l < 2; ++l) {
        int idx = t + l * 256;
        int r   = idx >> 2;           // output col 0..127
        int c4  = (idx & 3) << 2;
        float4 v = *(const float4*)&B[(size_t)(n0 + r) * KDIM + kb + c4];
        Bs[c4 + 0][r] = v.x; Bs[c4 + 1][r] = v.y;
        Bs[c4 + 2][r] = v.z; Bs[c4 + 3][r] = v.w;
      }
    } else {
      #pragma unroll
      for (int l = 0; l < 2; ++l) {
        int idx = t + l * 256;        // 512 float4 slots
        int k   = idx >> 5;           // 0..15
        int n4  = (idx & 31) << 2;    // 0..124
        *(float4*)&Bs[k][n4] = *(const float4*)&B[(size_t)(kb + k) * Ncols + n0 + n4];
      }
    }
    __syncthreads();
    // ---- compute ----
    #pragma unroll
    for (int k = 0; k < BK; ++k) {
      float a[8], b[8];
      *(float4*)&a[0] = *(const float4*)&As[k][ty * 8];
      *(float4*)&a[4] = *(const float4*)&As[k][ty * 8 + 4];
      *(float4*)&b[0] = *(const float4*)&Bs[k][tx * 8];
      *(float4*)&b[4] = *(const float4*)&Bs[k][tx * 8 + 4];
      #pragma unroll
      for (int i = 0; i < 8; ++i)
        #pragma unroll
        for (int j = 0; j < 8; ++j) acc[i][j] = fmaf(a[i], b[j], acc[i][j]);
    }
    __syncthreads();
  }

  if (!EPI_COS) {
    #pragma unroll
    for (int i = 0; i < 8; ++i) {
      int gr = m0 + ty * 8 + i;
      if (gr < M) {
        *(float4*)&C[(size_t)gr * Ncols + n0 + tx * 8]     = *(float4*)&acc[i][0];
        *(float4*)&C[(size_t)gr * Ncols + n0 + tx * 8 + 4] = *(float4*)&acc[i][4];
      }
    }
  } else {
    const int kchunk = blockIdx.y;            // 0..7
    float nm = norm_mu[kchunk];
    float muv[8];
    #pragma unroll
    for (int j = 0; j < 8; ++j) muv[j] = mu[kchunk * 128 + tx * 8 + j];
    #pragma unroll
    for (int i = 0; i < 8; ++i) {
      float num = 0.f, ss = 0.f;
      #pragma unroll
      for (int j = 0; j < 8; ++j) {
        float o = acc[i][j];
        num = fmaf(o, muv[j], num);
        ss  = fmaf(o, o, ss);
      }
      #pragma unroll
      for (int off = 1; off < 16; off <<= 1) {
        num += __shfl_xor(num, off, 64);
        ss  += __shfl_xor(ss,  off, 64);
      }
      if (tx == 0) {
        int gr = m0 + ty * 8 + i;
        if (gr < M) outcos[(size_t)gr * 8 + kchunk] = num / fmaxf(sqrtf(ss) * nm, 1e-8f);
      }
    }
  }
}

// ======================== per-node alpha dot products ========================
template<int H>
__global__ __launch_bounds__(256) void alpha_kernel(
    const float* __restrict__ h, const float* __restrict__ a_src,
    const float* __restrict__ a_dst, float* __restrict__ asrc,
    float* __restrict__ adst, int N)
{
  int lane = threadIdx.x & 63;
  int n = (blockIdx.x * blockDim.x + threadIdx.x) >> 6;
  if (n >= N) return;
  float4 hv = *(const float4*)&h[(size_t)n * 256 + lane * 4];
  float4 as = *(const float4*)&a_src[lane * 4];
  float4 ad = *(const float4*)&a_dst[lane * 4];
  float s = hv.x * as.x + hv.y * as.y + hv.z * as.z + hv.w * as.w;
  float d = hv.x * ad.x + hv.y * ad.y + hv.z * ad.z + hv.w * ad.w;
  const int L = 64 / H;                 // lanes per head segment
  #pragma unroll
  for (int off = 1; off < L; off <<= 1) {
    s += __shfl_xor(s, off, 64);
    d += __shfl_xor(d, off, 64);
  }
  if ((lane & (L - 1)) == 0) {
    int hh = lane / L;
    asrc[(size_t)n * H + hh] = s;
    adst[(size_t)n * H + hh] = d;
  }
}

// ======================== GAT aggregation (one wave per node) ========================
template<int H, bool OUT_LRELU>
__global__ __launch_bounds__(256) void agg_kernel(
    const float* __restrict__ hin, const float* __restrict__ asrc,
    const float* __restrict__ adst, const int* __restrict__ rowptr,
    const int* __restrict__ colsrc, const float* __restrict__ bias,
    float* __restrict__ outp, int N)
{
  int wid  = threadIdx.x >> 6;
  int lane = threadIdx.x & 63;
  int n = blockIdx.x * 4 + wid;
  if (n >= N) return;
  const int head = (H == 2) ? (lane >> 5) : 0;
  int beg = rowptr[n], end = rowptr[n + 1];

  float adst_l[H], m[H];
  #pragma unroll
  for (int h = 0; h < H; ++h) {
    adst_l[h] = adst[(size_t)n * H + h];
    m[h] = lrelu(asrc[(size_t)n * H + h] + adst_l[h], 0.2f);   // self-loop logit
  }
  // pass 1: segment max
  for (int j = beg; j < end; ++j) {
    int s = colsrc[j];
    #pragma unroll
    for (int h = 0; h < H; ++h) {
      float e = lrelu(asrc[(size_t)s * H + h] + adst_l[h], 0.2f);
      m[h] = fmaxf(m[h], e);
    }
  }
  // pass 2: accumulate
  float ssum[H];
  float pself[H];
  #pragma unroll
  for (int h = 0; h < H; ++h) {
    float e = lrelu(asrc[(size_t)n * H + h] + adst_l[h], 0.2f);
    pself[h] = __expf(e - m[h]);
    ssum[h] = pself[h];
  }
  float4 hv = *(const float4*)&hin[(size_t)n * 256 + lane * 4];
  float p = pself[head];
  float ax = hv.x * p, ay = hv.y * p, az = hv.z * p, aw = hv.w * p;
  for (int j = beg; j < end; ++j) {
    int s = colsrc[j];
    float pj[H];
    #pragma unroll
    for (int h = 0; h < H; ++h) {
      float e = lrelu(asrc[(size_t)s * H + h] + adst_l[h], 0.2f);
      pj[h] = __expf(e - m[h]);
      ssum[h] += pj[h];
    }
    float4 v = *(const float4*)&hin[(size_t)s * 256 + lane * 4];
    float pp = pj[head];
    ax = fmaf(v.x, pp, ax); ay = fmaf(v.y, pp, ay);
    az = fmaf(v.z, pp, az); aw = fmaf(v.w, pp, aw);
  }
  float inv = 1.0f / ssum[head];
  float4 bv = *(const float4*)&bias[lane * 4];
  float ox = ax * inv + bv.x, oy = ay * inv + bv.y;
  float oz = az * inv + bv.z, ow = aw * inv + bv.w;
  if (OUT_LRELU) {
    ox = lrelu(ox, 0.01f); oy = lrelu(oy, 0.01f);
    oz = lrelu(oz, 0.01f); ow = lrelu(ow, 0.01f);
  }
  float4 o = make_float4(ox, oy, oz, ow);
  *(float4*)&outp[(size_t)n * 256 + lane * 4] = o;
}

// ======================== mu norms ========================
__global__ __launch_bounds__(64) void munorm_kernel(const float* __restrict__ mu,
                                                    float* __restrict__ norm_mu) {
  int lane = threadIdx.x;
  for (int k = 0; k < 8; ++k) {
    float v0 = mu[k * 128 + lane];
    float v1 = mu[k * 128 + 64 + lane];
    float s = v0 * v0 + v1 * v1;
    #pragma unroll
    for (int off = 1; off < 64; off <<= 1) s += __shfl_xor(s, off, 64);
    if (lane == 0) norm_mu[k] = sqrtf(s);
  }
}

// ======================== launch ========================
extern "C" void kernel_launch(void* const* d_in, const int* in_sizes, int n_in,
                              void* d_out, int out_size, void* d_ws, size_t ws_size,
                              hipStream_t stream) {
  const float* x      = (const float*)d_in[0];
  const int*   ei     = (const int*)  d_in[1];
  const float* W1     = (const float*)d_in[2];
  const float* a_src1 = (const float*)d_in[3];
  const float* a_dst1 = (const float*)d_in[4];
  const float* b1     = (const float*)d_in[5];
  const float* W2     = (const float*)d_in[6];
  const float* a_src2 = (const float*)d_in[7];
  const float* a_dst2 = (const float*)d_in[8];
  const float* b2     = (const float*)d_in[9];
  const float* g      = (const float*)d_in[10];
  const float* mu     = (const float*)d_in[11];

  const int N = in_sizes[0] / KDIM;     // 50000
  const int E = in_sizes[1] / 2;        // 800000
  const int* src = ei;
  const int* dst = ei + E;

  // workspace layout
  float* fws   = (float*)d_ws;
  float* h1    = fws;                         // N*256
  float* out1  = h1   + (size_t)N * 256;      // N*256
  float* h2    = out1 + (size_t)N * 256;      // N*256
  float* out2  = h1;                          // reuse h1 after layer-1 agg
  float* asrc1 = h2    + (size_t)N * 256;     // N*2
  float* adst1 = asrc1 + (size_t)N * 2;       // N*2
  float* asrc2 = adst1 + (size_t)N * 2;       // N
  float* adst2 = asrc2 + (size_t)N;           // N
  float* nmu   = adst2 + (size_t)N;           // 8
  int* deg     = (int*)(nmu + 8);             // N
  int* rowptr  = deg + N;                     // N+1
  int* cursor  = rowptr + N + 1;              // N
  int* colsrc  = cursor + N;                  // E

  // ---- CSR build ----
  hipMemsetAsync(deg, 0, (size_t)N * sizeof(int), stream);
  deg_kernel<<<(E + 255) / 256, 256, 0, stream>>>(dst, deg, E);
  scan_kernel<<<1, 1024, 0, stream>>>(deg, rowptr, N);
  hipMemcpyAsync(cursor, rowptr, (size_t)N * sizeof(int), hipMemcpyDeviceToDevice, stream);
  fill_kernel<<<(E + 255) / 256, 256, 0, stream>>>(src, dst, cursor, colsrc, E);

  const int gm = (N + 127) / 128;

  // ---- layer 1 ----
  gemm128<true, false><<<dim3(gm, 2), 256, 0, stream>>>(x, W1, h1, nullptr, nullptr, nullptr, N, 256);
  alpha_kernel<2><<<(N + 3) / 4, 256, 0, stream>>>(h1, a_src1, a_dst1, asrc1, adst1, N);
  agg_kernel<2, true><<<(N + 3) / 4, 256, 0, stream>>>(h1, asrc1, adst1, rowptr, colsrc, b1, out1, N);

  // ---- layer 2 ----
  gemm128<true, false><<<dim3(gm, 2), 256, 0, stream>>>(out1, W2, h2, nullptr, nullptr, nullptr, N, 256);
  alpha_kernel<1><<<(N + 3) / 4, 256, 0, stream>>>(h2, a_src2, a_dst2, asrc2, adst2, N);
  agg_kernel<1, false><<<(N + 3) / 4, 256, 0, stream>>>(h2, asrc2, adst2, rowptr, colsrc, b2, out2, N);

  // ---- projection + cosine ----
  munorm_kernel<<<1, 64, 0, stream>>>(mu, nmu);
  gemm128<false, true><<<dim3(gm, 8), 256, 0, stream>>>(out2, g, nullptr, mu, nmu, (float*)d_out, N, 1024);
}

// Round 2
// 693.583 us; speedup vs baseline: 1.6284x; 1.6284x over previous
//
#include <hip/hip_runtime.h>
#include <math.h>

typedef short s16x8 __attribute__((ext_vector_type(8)));
typedef float f32x4 __attribute__((ext_vector_type(4)));

__device__ __forceinline__ float lrelu(float x, float s) { return x > 0.0f ? x : s * x; }

// RNE f32 -> bf16 (bit-level, avoids __hip_bfloat16 API)
__device__ __forceinline__ unsigned short f2bf(float f) {
  unsigned int u = __float_as_uint(f);
  u = (u + 0x7FFFu + ((u >> 16) & 1u)) >> 16;
  return (unsigned short)u;
}
__device__ __forceinline__ float bf2f(unsigned short h) {
  return __uint_as_float(((unsigned int)h) << 16);
}

// async global->LDS, 16B per lane; LDS dest is wave-uniform base + lane*16
__device__ __forceinline__ void gload_lds16(void* lds, const void* g) {
  __builtin_amdgcn_global_load_lds(
      (const __attribute__((address_space(1))) unsigned int*)g,
      (__attribute__((address_space(3))) unsigned int*)lds, 16, 0, 0);
}

// ======================== CSR build ========================
__global__ void deg_kernel(const int* __restrict__ dst, int* __restrict__ deg, int E) {
  int e = blockIdx.x * blockDim.x + threadIdx.x;
  if (e < E) atomicAdd(&deg[dst[e]], 1);
}

__global__ __launch_bounds__(1024) void scan_kernel(const int* __restrict__ deg,
                                                    int* __restrict__ rowptr, int N) {
  __shared__ int sums[1024];
  int t = threadIdx.x;
  int CH = (N + 1023) / 1024;
  int base = t * CH;
  int s = 0;
  for (int i = 0; i < CH; ++i) { int idx = base + i; if (idx < N) s += deg[idx]; }
  sums[t] = s;
  __syncthreads();
  for (int off = 1; off < 1024; off <<= 1) {
    int v = (t >= off) ? sums[t - off] : 0;
    __syncthreads();
    sums[t] += v;
    __syncthreads();
  }
  int run = (t == 0) ? 0 : sums[t - 1];
  for (int i = 0; i < CH; ++i) {
    int idx = base + i;
    if (idx < N) { rowptr[idx] = run; run += deg[idx]; }
  }
  if (t == 1023) rowptr[N] = sums[1023];
}

__global__ void fill_kernel(const int* __restrict__ src, const int* __restrict__ dst,
                            int* __restrict__ cursor, int* __restrict__ colsrc, int E) {
  int e = blockIdx.x * blockDim.x + threadIdx.x;
  if (e < E) {
    int d = dst[e];
    int pos = atomicAdd(&cursor[d], 1);
    colsrc[pos] = src[e];
  }
}

// ======================== f32 -> bf16 conversions ========================
// rows: [nrows][256] f32 -> [prows][256] bf16, zero-fill pad rows
__global__ void cvt_rows_kernel(const float* __restrict__ src, unsigned short* __restrict__ dst,
                                int nrows, int prows) {
  int t = blockIdx.x * blockDim.x + threadIdx.x;
  int row = t >> 6;
  int c = (t & 63) * 4;
  if (row >= prows) return;
  float4 v = make_float4(0.f, 0.f, 0.f, 0.f);
  if (row < nrows) v = *(const float4*)&src[(size_t)row * 256 + c];
  ushort4 o;
  o.x = f2bf(v.x); o.y = f2bf(v.y); o.z = f2bf(v.z); o.w = f2bf(v.w);
  *(ushort4*)&dst[(size_t)row * 256 + c] = o;
}

// g [256][1024] f32 -> gT [1024][256] bf16
__global__ void cvt_gT_kernel(const float* __restrict__ g, unsigned short* __restrict__ gT) {
  int idx = blockIdx.x * blockDim.x + threadIdx.x;  // 0..262143
  int k = idx >> 10, n = idx & 1023;
  gT[(size_t)n * 256 + k] = f2bf(g[idx]);
}

// ======================== bf16 MFMA GEMM, 128x128 tile, BK=64 ========================
// A: [Mp][256] bf16 row-major (padded rows).  B: [Ntot][256] bf16 (B^T layout: row = out col).
// 4 waves, wave w owns rows w*32..w*32+31 x all 128 cols (2 m-frags x 8 n-frags of 16x16).
// LDS linear [row][64 ushort]; 16B chunk slot XOR-swizzled with (row&7): staged via
// pre-swizzled GLOBAL source (rule 21), read with same XOR -> conflict-free ds_read_b128.
// EPI=0: store C as bf16 [Mp][256].  EPI=1: fused cosine epilogue (Ncols tile == K-chunk).
template<int EPI>
__global__ __launch_bounds__(256, 2) void gemm_bf16(
    const unsigned short* __restrict__ A, const unsigned short* __restrict__ B,
    unsigned short* __restrict__ Cb,
    const float* __restrict__ mu, const float* __restrict__ nmu,
    float* __restrict__ outcos, int M)
{
  __shared__ unsigned short As[128 * 64];
  __shared__ unsigned short Bs[128 * 64];
  const int t = threadIdx.x;
  const int w = t >> 6;
  const int l = t & 63;
  const int m0 = blockIdx.x * 128;
  const int n0 = blockIdx.y * 128;

  f32x4 acc[2][8];
  #pragma unroll
  for (int i = 0; i < 2; ++i)
    #pragma unroll
    for (int j = 0; j < 8; ++j) acc[i][j] = (f32x4){0.f, 0.f, 0.f, 0.f};

  const unsigned char* Ab = (const unsigned char*)A;
  const unsigned char* Bb = (const unsigned char*)B;
  unsigned char* AsB = (unsigned char*)As;
  unsigned char* BsB = (unsigned char*)Bs;

  const int srow = l >> 3;               // 0..7: row within 8-row segment
  const int gchk = (l & 7) ^ srow;       // pre-swizzled global 16B-chunk index

  for (int kb = 0; kb < 256; kb += 64) {
    #pragma unroll
    for (int i = 0; i < 4; ++i) {
      int seg = w * 4 + i;               // 16 segments of 8 rows each
      int row = seg * 8 + srow;          // local row 0..127
      gload_lds16(AsB + seg * 1024,
                  Ab + (size_t)(m0 + row) * 512 + kb * 2 + gchk * 16);
      gload_lds16(BsB + seg * 1024,
                  Bb + (size_t)(n0 + row) * 512 + kb * 2 + gchk * 16);
    }
    asm volatile("s_waitcnt vmcnt(0)" ::: "memory");
    __syncthreads();

    const int rl = l & 15;
    const int kc = l >> 4;               // 0..3
    #pragma unroll
    for (int ks = 0; ks < 2; ++ks) {
      s16x8 af[2], bfr[8];
      #pragma unroll
      for (int mf = 0; mf < 2; ++mf) {
        int r = w * 32 + mf * 16 + rl;
        int slot = (ks * 4 + kc) ^ (r & 7);
        af[mf] = *(const s16x8*)&As[r * 64 + slot * 8];
      }
      #pragma unroll
      for (int nf = 0; nf < 8; ++nf) {
        int r = nf * 16 + rl;
        int slot = (ks * 4 + kc) ^ (r & 7);
        bfr[nf] = *(const s16x8*)&Bs[r * 64 + slot * 8];
      }
      #pragma unroll
      for (int mf = 0; mf < 2; ++mf)
        #pragma unroll
        for (int nf = 0; nf < 8; ++nf)
          acc[mf][nf] = __builtin_amdgcn_mfma_f32_16x16x32_bf16(af[mf], bfr[nf], acc[mf][nf], 0, 0, 0);
    }
    __syncthreads();
  }

  if (EPI == 0) {
    // C/D layout: col = lane&15, row = (lane>>4)*4 + reg  [m89/m91 verified]
    #pragma unroll
    for (int mf = 0; mf < 2; ++mf)
      #pragma unroll
      for (int nf = 0; nf < 8; ++nf)
        #pragma unroll
        for (int j = 0; j < 4; ++j) {
          int r = m0 + w * 32 + mf * 16 + (l >> 4) * 4 + j;
          int c = n0 + nf * 16 + (l & 15);
          Cb[(size_t)r * 256 + c] = f2bf(acc[mf][nf][j]);
        }
  } else {
    const int kchunk = blockIdx.y;       // 0..7
    float nm = nmu[kchunk];
    float mv[8];
    #pragma unroll
    for (int nf = 0; nf < 8; ++nf) mv[nf] = mu[kchunk * 128 + nf * 16 + (l & 15)];
    #pragma unroll
    for (int mf = 0; mf < 2; ++mf)
      #pragma unroll
      for (int j = 0; j < 4; ++j) {
        float num = 0.f, ss = 0.f;
        #pragma unroll
        for (int nf = 0; nf < 8; ++nf) {
          float o = acc[mf][nf][j];
          num = fmaf(o, mv[nf], num);
          ss  = fmaf(o, o, ss);
        }
        #pragma unroll
        for (int off = 1; off < 16; off <<= 1) {
          num += __shfl_xor(num, off, 64);
          ss  += __shfl_xor(ss, off, 64);
        }
        if ((l & 15) == 0) {
          int r = m0 + w * 32 + mf * 16 + (l >> 4) * 4 + j;
          if (r < M) outcos[(size_t)r * 8 + kchunk] = num / fmaxf(sqrtf(ss) * nm, 1e-8f);
        }
      }
  }
}

// ======================== per-node alpha dot products (bf16 h) ========================
template<int H>
__global__ __launch_bounds__(256) void alpha_kernel(
    const unsigned short* __restrict__ h, const float* __restrict__ a_src,
    const float* __restrict__ a_dst, float* __restrict__ asrc,
    float* __restrict__ adst, int N)
{
  int lane = threadIdx.x & 63;
  int n = (blockIdx.x * blockDim.x + threadIdx.x) >> 6;
  if (n >= N) return;
  ushort4 hv = *(const ushort4*)&h[(size_t)n * 256 + lane * 4];
  float4 as = *(const float4*)&a_src[lane * 4];
  float4 ad = *(const float4*)&a_dst[lane * 4];
  float h0 = bf2f(hv.x), h1 = bf2f(hv.y), h2 = bf2f(hv.z), h3 = bf2f(hv.w);
  float s = h0 * as.x + h1 * as.y + h2 * as.z + h3 * as.w;
  float d = h0 * ad.x + h1 * ad.y + h2 * ad.z + h3 * ad.w;
  const int L = 64 / H;
  #pragma unroll
  for (int off = 1; off < L; off <<= 1) {
    s += __shfl_xor(s, off, 64);
    d += __shfl_xor(d, off, 64);
  }
  if ((lane & (L - 1)) == 0) {
    int hh = lane / L;
    asrc[(size_t)n * H + hh] = s;
    adst[(size_t)n * H + hh] = d;
  }
}

// ======================== GAT aggregation (one wave per node, bf16 h) ========================
template<int H, bool OUT_LRELU>
__global__ __launch_bounds__(256) void agg_kernel(
    const unsigned short* __restrict__ hin, const float* __restrict__ asrc,
    const float* __restrict__ adst, const int* __restrict__ rowptr,
    const int* __restrict__ colsrc, const float* __restrict__ bias,
    unsigned short* __restrict__ outp, int N)
{
  int wid  = threadIdx.x >> 6;
  int lane = threadIdx.x & 63;
  int n = blockIdx.x * 4 + wid;
  if (n >= N) return;
  const int head = (H == 2) ? (lane >> 5) : 0;
  int beg = rowptr[n], end = rowptr[n + 1];

  float adst_l[H], m[H];
  #pragma unroll
  for (int h = 0; h < H; ++h) {
    adst_l[h] = adst[(size_t)n * H + h];
    m[h] = lrelu(asrc[(size_t)n * H + h] + adst_l[h], 0.2f);   // self-loop logit
  }
  for (int j = beg; j < end; ++j) {                  // pass 1: segment max
    int s = colsrc[j];
    #pragma unroll
    for (int h = 0; h < H; ++h) {
      float e = lrelu(asrc[(size_t)s * H + h] + adst_l[h], 0.2f);
      m[h] = fmaxf(m[h], e);
    }
  }
  float ssum[H], pself[H];
  #pragma unroll
  for (int h = 0; h < H; ++h) {
    float e = lrelu(asrc[(size_t)n * H + h] + adst_l[h], 0.2f);
    pself[h] = __expf(e - m[h]);
    ssum[h] = pself[h];
  }
  ushort4 hv = *(const ushort4*)&hin[(size_t)n * 256 + lane * 4];
  float p = (H == 2 && head) ? pself[1] : pself[0];  // avoid runtime array index (rule #20)
  float ax = bf2f(hv.x) * p, ay = bf2f(hv.y) * p, az = bf2f(hv.z) * p, aw = bf2f(hv.w) * p;
  for (int j = beg; j < end; ++j) {                  // pass 2: accumulate
    int s = colsrc[j];
    float pj[H];
    #pragma unroll
    for (int h = 0; h < H; ++h) {
      float e = lrelu(asrc[(size_t)s * H + h] + adst_l[h], 0.2f);
      pj[h] = __expf(e - m[h]);
      ssum[h] += pj[h];
    }
    ushort4 v4 = *(const ushort4*)&hin[(size_t)s * 256 + lane * 4];
    float pp = (H == 2 && head) ? pj[1] : pj[0];
    ax = fmaf(bf2f(v4.x), pp, ax); ay = fmaf(bf2f(v4.y), pp, ay);
    az = fmaf(bf2f(v4.z), pp, az); aw = fmaf(bf2f(v4.w), pp, aw);
  }
  float sv = (H == 2 && head) ? ssum[1] : ssum[0];
  float inv = 1.0f / sv;
  float4 bv = *(const float4*)&bias[lane * 4];
  float ox = ax * inv + bv.x, oy = ay * inv + bv.y;
  float oz = az * inv + bv.z, ow = aw * inv + bv.w;
  if (OUT_LRELU) {
    ox = lrelu(ox, 0.01f); oy = lrelu(oy, 0.01f);
    oz = lrelu(oz, 0.01f); ow = lrelu(ow, 0.01f);
  }
  ushort4 o;
  o.x = f2bf(ox); o.y = f2bf(oy); o.z = f2bf(oz); o.w = f2bf(ow);
  *(ushort4*)&outp[(size_t)n * 256 + lane * 4] = o;
}

// ======================== mu norms ========================
__global__ __launch_bounds__(64) void munorm_kernel(const float* __restrict__ mu,
                                                    float* __restrict__ norm_mu) {
  int lane = threadIdx.x;
  for (int k = 0; k < 8; ++k) {
    float v0 = mu[k * 128 + lane];
    float v1 = mu[k * 128 + 64 + lane];
    float s = v0 * v0 + v1 * v1;
    #pragma unroll
    for (int off = 1; off < 64; off <<= 1) s += __shfl_xor(s, off, 64);
    if (lane == 0) norm_mu[k] = sqrtf(s);
  }
}

// ======================== launch ========================
extern "C" void kernel_launch(void* const* d_in, const int* in_sizes, int n_in,
                              void* d_out, int out_size, void* d_ws, size_t ws_size,
                              hipStream_t stream) {
  const float* x      = (const float*)d_in[0];
  const int*   ei     = (const int*)  d_in[1];
  const float* W1     = (const float*)d_in[2];
  const float* a_src1 = (const float*)d_in[3];
  const float* a_dst1 = (const float*)d_in[4];
  const float* b1     = (const float*)d_in[5];
  const float* W2     = (const float*)d_in[6];
  const float* a_src2 = (const float*)d_in[7];
  const float* a_dst2 = (const float*)d_in[8];
  const float* b2     = (const float*)d_in[9];
  const float* g      = (const float*)d_in[10];
  const float* mu     = (const float*)d_in[11];

  const int N  = in_sizes[0] / 256;            // 50000
  const int E  = in_sizes[1] / 2;              // 800000
  const int Mp = ((N + 127) / 128) * 128;      // 50048
  const int* src = ei;
  const int* dst = ei + E;

  // ---- workspace layout (bf16 tensors first, all 16B-aligned sizes) ----
  unsigned short* us = (unsigned short*)d_ws;
  size_t off = 0;
  unsigned short* xb  = us + off; off += (size_t)Mp * 256;   // x bf16 (reused as out2b)
  unsigned short* h1b = us + off; off += (size_t)Mp * 256;
  unsigned short* o1b = us + off; off += (size_t)Mp * 256;
  unsigned short* h2b = us + off; off += (size_t)Mp * 256;
  unsigned short* o2b = xb;                                  // alias: xb dead after gemm1
  float* f = (float*)(us + off);
  size_t fo = 0;
  float* asrc1 = f + fo; fo += (size_t)N * 2;
  float* adst1 = f + fo; fo += (size_t)N * 2;
  float* asrc2 = f + fo; fo += N;
  float* adst2 = f + fo; fo += N;
  float* nmu   = f + fo; fo += 8;
  int* deg    = (int*)(f + fo);
  int* rowptr = deg + N;
  int* cursor = rowptr + N + 1;
  int* colsrc = cursor + N;
  unsigned short* w1b = (unsigned short*)(colsrc + E);
  unsigned short* w2b = w1b + 256 * 256;
  unsigned short* gTb = w2b + 256 * 256;

  // ---- CSR build ----
  hipMemsetAsync(deg, 0, (size_t)N * sizeof(int), stream);
  deg_kernel<<<(E + 255) / 256, 256, 0, stream>>>(dst, deg, E);
  scan_kernel<<<1, 1024, 0, stream>>>(deg, rowptr, N);
  hipMemcpyAsync(cursor, rowptr, (size_t)N * sizeof(int), hipMemcpyDeviceToDevice, stream);
  fill_kernel<<<(E + 255) / 256, 256, 0, stream>>>(src, dst, cursor, colsrc, E);

  // ---- conversions ----
  cvt_rows_kernel<<<Mp / 4, 256, 0, stream>>>(x, xb, N, Mp);
  cvt_rows_kernel<<<64, 256, 0, stream>>>(W1, w1b, 256, 256);
  cvt_rows_kernel<<<64, 256, 0, stream>>>(W2, w2b, 256, 256);
  cvt_gT_kernel<<<1024, 256, 0, stream>>>(g, gTb);
  munorm_kernel<<<1, 64, 0, stream>>>(mu, nmu);

  const int gm = Mp / 128;   // 391

  // ---- layer 1 ----
  gemm_bf16<0><<<dim3(gm, 2), 256, 0, stream>>>(xb, w1b, h1b, nullptr, nullptr, nullptr, N);
  alpha_kernel<2><<<(N + 3) / 4, 256, 0, stream>>>(h1b, a_src1, a_dst1, asrc1, adst1, N);
  agg_kernel<2, true><<<(N + 3) / 4, 256, 0, stream>>>(h1b, asrc1, adst1, rowptr, colsrc, b1, o1b, N);

  // ---- layer 2 ----
  gemm_bf16<0><<<dim3(gm, 2), 256, 0, stream>>>(o1b, w2b, h2b, nullptr, nullptr, nullptr, N);
  alpha_kernel<1><<<(N + 3) / 4, 256, 0, stream>>>(h2b, a_src2, a_dst2, asrc2, adst2, N);
  agg_kernel<1, false><<<(N + 3) / 4, 256, 0, stream>>>(h2b, asrc2, adst2, rowptr, colsrc, b2, o2b, N);

  // ---- projection + fused cosine ----
  gemm_bf16<1><<<dim3(gm, 8), 256, 0, stream>>>(o2b, gTb, nullptr, mu, nmu, (float*)d_out, N);
}

// Round 3
// 502.281 us; speedup vs baseline: 2.2486x; 1.3809x over previous
//
#include <hip/hip_runtime.h>
#include <math.h>

typedef short s16x8 __attribute__((ext_vector_type(8)));
typedef float f32x4 __attribute__((ext_vector_type(4)));

__device__ __forceinline__ float lrelu(float x, float s) { return x > 0.0f ? x : s * x; }

// RNE f32 -> bf16 (bit-level)
__device__ __forceinline__ unsigned short f2bf(float f) {
  unsigned int u = __float_as_uint(f);
  u = (u + 0x7FFFu + ((u >> 16) & 1u)) >> 16;
  return (unsigned short)u;
}
__device__ __forceinline__ float bf2f(unsigned short h) {
  return __uint_as_float(((unsigned int)h) << 16);
}

// async global->LDS, 16B per lane; LDS dest is wave-uniform base + lane*16
__device__ __forceinline__ void gload_lds16(void* lds, const void* g) {
  __builtin_amdgcn_global_load_lds(
      (const __attribute__((address_space(1))) unsigned int*)g,
      (__attribute__((address_space(3))) unsigned int*)lds, 16, 0, 0);
}

// ======================== CSR build ========================
__global__ void deg_kernel(const int* __restrict__ dst, int* __restrict__ deg, int E) {
  int e = blockIdx.x * blockDim.x + threadIdx.x;
  if (e < E) atomicAdd(&deg[dst[e]], 1);
}

__global__ __launch_bounds__(1024) void scan_kernel(const int* __restrict__ deg,
                                                    int* __restrict__ rowptr, int N) {
  __shared__ int sums[1024];
  int t = threadIdx.x;
  int CH = (N + 1023) / 1024;
  int base = t * CH;
  int s = 0;
  for (int i = 0; i < CH; ++i) { int idx = base + i; if (idx < N) s += deg[idx]; }
  sums[t] = s;
  __syncthreads();
  for (int off = 1; off < 1024; off <<= 1) {
    int v = (t >= off) ? sums[t - off] : 0;
    __syncthreads();
    sums[t] += v;
    __syncthreads();
  }
  int run = (t == 0) ? 0 : sums[t - 1];
  for (int i = 0; i < CH; ++i) {
    int idx = base + i;
    if (idx < N) { rowptr[idx] = run; run += deg[idx]; }
  }
  if (t == 1023) rowptr[N] = sums[1023];
}

__global__ void fill_kernel(const int* __restrict__ src, const int* __restrict__ dst,
                            int* __restrict__ cursor, int* __restrict__ colsrc, int E) {
  int e = blockIdx.x * blockDim.x + threadIdx.x;
  if (e < E) {
    int d = dst[e];
    int pos = atomicAdd(&cursor[d], 1);
    colsrc[pos] = src[e];
  }
}

// ======================== f32 -> bf16 conversions ========================
__global__ void cvt_rows_kernel(const float* __restrict__ src, unsigned short* __restrict__ dst,
                                int nrows, int prows) {
  int t = blockIdx.x * blockDim.x + threadIdx.x;
  int row = t >> 6;
  int c = (t & 63) * 4;
  if (row >= prows) return;
  float4 v = make_float4(0.f, 0.f, 0.f, 0.f);
  if (row < nrows) v = *(const float4*)&src[(size_t)row * 256 + c];
  ushort4 o;
  o.x = f2bf(v.x); o.y = f2bf(v.y); o.z = f2bf(v.z); o.w = f2bf(v.w);
  *(ushort4*)&dst[(size_t)row * 256 + c] = o;
}

__global__ void cvt_gT_kernel(const float* __restrict__ g, unsigned short* __restrict__ gT) {
  int idx = blockIdx.x * blockDim.x + threadIdx.x;  // 0..262143
  int k = idx >> 10, n = idx & 1023;
  gT[(size_t)n * 256 + k] = f2bf(g[idx]);
}

// ======================== bf16 MFMA GEMM, 128x128 tile, BK=64 ========================
// A: [Mp][256] bf16. B: [Ntot][256] bf16 (row = out col). 4 waves; wave w owns rows
// w*32..+31 x 128 cols. LDS 16B-chunk XOR-swizzled via pre-swizzled global src (rule 21).
// EPI=0: store C bf16 [Mp][256]; AH>0: fused a_src/a_dst dot products.
//   AH==2: blockIdx.y == head, direct store. AH==1: atomicAdd partials (zeroed before).
// EPI=1: fused cosine epilogue (block col-tile == K-chunk of 128).
template<int EPI, int AH>
__global__ __launch_bounds__(256, 2) void gemm_bf16(
    const unsigned short* __restrict__ A, const unsigned short* __restrict__ B,
    unsigned short* __restrict__ Cb,
    const float* __restrict__ avs, const float* __restrict__ avd,
    float* __restrict__ asrcO, float* __restrict__ adstO,
    const float* __restrict__ mu, const float* __restrict__ nmu,
    float* __restrict__ outcos, int M)
{
  __shared__ unsigned short As[128 * 64];
  __shared__ unsigned short Bs[128 * 64];
  const int t = threadIdx.x;
  const int w = t >> 6;
  const int l = t & 63;
  const int m0 = blockIdx.x * 128;
  const int n0 = blockIdx.y * 128;

  f32x4 acc[2][8];
  #pragma unroll
  for (int i = 0; i < 2; ++i)
    #pragma unroll
    for (int j = 0; j < 8; ++j) acc[i][j] = (f32x4){0.f, 0.f, 0.f, 0.f};

  const unsigned char* Ab = (const unsigned char*)A;
  const unsigned char* Bb = (const unsigned char*)B;
  unsigned char* AsB = (unsigned char*)As;
  unsigned char* BsB = (unsigned char*)Bs;

  const int srow = l >> 3;               // 0..7: row within 8-row segment
  const int gchk = (l & 7) ^ srow;       // pre-swizzled global 16B-chunk index

  for (int kb = 0; kb < 256; kb += 64) {
    #pragma unroll
    for (int i = 0; i < 4; ++i) {
      int seg = w * 4 + i;               // 16 segments of 8 rows each
      int row = seg * 8 + srow;          // local row 0..127
      gload_lds16(AsB + seg * 1024,
                  Ab + (size_t)(m0 + row) * 512 + kb * 2 + gchk * 16);
      gload_lds16(BsB + seg * 1024,
                  Bb + (size_t)(n0 + row) * 512 + kb * 2 + gchk * 16);
    }
    asm volatile("s_waitcnt vmcnt(0)" ::: "memory");
    __syncthreads();

    const int rl = l & 15;
    const int kc = l >> 4;               // 0..3
    #pragma unroll
    for (int ks = 0; ks < 2; ++ks) {
      s16x8 af[2], bfr[8];
      #pragma unroll
      for (int mf = 0; mf < 2; ++mf) {
        int r = w * 32 + mf * 16 + rl;
        int slot = (ks * 4 + kc) ^ (r & 7);
        af[mf] = *(const s16x8*)&As[r * 64 + slot * 8];
      }
      #pragma unroll
      for (int nf = 0; nf < 8; ++nf) {
        int r = nf * 16 + rl;
        int slot = (ks * 4 + kc) ^ (r & 7);
        bfr[nf] = *(const s16x8*)&Bs[r * 64 + slot * 8];
      }
      #pragma unroll
      for (int mf = 0; mf < 2; ++mf)
        #pragma unroll
        for (int nf = 0; nf < 8; ++nf)
          acc[mf][nf] = __builtin_amdgcn_mfma_f32_16x16x32_bf16(af[mf], bfr[nf], acc[mf][nf], 0, 0, 0);
    }
    __syncthreads();
  }

  if (EPI == 0) {
    // C/D layout: col = lane&15, row = (lane>>4)*4 + reg  [m89/m91 verified]
    #pragma unroll
    for (int mf = 0; mf < 2; ++mf)
      #pragma unroll
      for (int nf = 0; nf < 8; ++nf)
        #pragma unroll
        for (int j = 0; j < 4; ++j) {
          int r = m0 + w * 32 + mf * 16 + (l >> 4) * 4 + j;
          int c = n0 + nf * 16 + (l & 15);
          Cb[(size_t)r * 256 + c] = f2bf(acc[mf][nf][j]);
        }
    if (AH > 0) {
      float avS[8], avD[8];
      #pragma unroll
      for (int nf = 0; nf < 8; ++nf) {
        avS[nf] = avs[n0 + nf * 16 + (l & 15)];
        avD[nf] = avd[n0 + nf * 16 + (l & 15)];
      }
      #pragma unroll
      for (int mf = 0; mf < 2; ++mf)
        #pragma unroll
        for (int j = 0; j < 4; ++j) {
          float ds = 0.f, dd = 0.f;
          #pragma unroll
          for (int nf = 0; nf < 8; ++nf) {
            float o = acc[mf][nf][j];
            ds = fmaf(o, avS[nf], ds);
            dd = fmaf(o, avD[nf], dd);
          }
          #pragma unroll
          for (int off = 1; off < 16; off <<= 1) {
            ds += __shfl_xor(ds, off, 64);
            dd += __shfl_xor(dd, off, 64);
          }
          if ((l & 15) == 0) {
            int r = m0 + w * 32 + mf * 16 + (l >> 4) * 4 + j;
            if (r < M) {
              if (AH == 2) {
                asrcO[(size_t)r * 2 + blockIdx.y] = ds;
                adstO[(size_t)r * 2 + blockIdx.y] = dd;
              } else {
                atomicAdd(&asrcO[r], ds);
                atomicAdd(&adstO[r], dd);
              }
            }
          }
        }
    }
  } else {
    const int kchunk = blockIdx.y;       // 0..7
    float nm = nmu[kchunk];
    float mv[8];
    #pragma unroll
    for (int nf = 0; nf < 8; ++nf) mv[nf] = mu[kchunk * 128 + nf * 16 + (l & 15)];
    #pragma unroll
    for (int mf = 0; mf < 2; ++mf)
      #pragma unroll
      for (int j = 0; j < 4; ++j) {
        float num = 0.f, ss = 0.f;
        #pragma unroll
        for (int nf = 0; nf < 8; ++nf) {
          float o = acc[mf][nf][j];
          num = fmaf(o, mv[nf], num);
          ss  = fmaf(o, o, ss);
        }
        #pragma unroll
        for (int off = 1; off < 16; off <<= 1) {
          num += __shfl_xor(num, off, 64);
          ss  += __shfl_xor(ss, off, 64);
        }
        if ((l & 15) == 0) {
          int r = m0 + w * 32 + mf * 16 + (l >> 4) * 4 + j;
          if (r < M) outcos[(size_t)r * 8 + kchunk] = num / fmaxf(sqrtf(ss) * nm, 1e-8f);
        }
      }
  }
}

// ======================== GAT aggregation ========================
// One wave per node. Lane-parallel chunked online softmax (64 edges/chunk),
// then gather with 16B/lane (short8), 32 lanes per row => 2 edges per wave-step,
// unrolled x2 (4 row-gathers in flight). Halves merged at the end.
template<int H, bool OUT_LRELU>
__global__ __launch_bounds__(256) void agg_kernel(
    const unsigned short* __restrict__ hin, const float* __restrict__ asrc,
    const float* __restrict__ adst, const int* __restrict__ rowptr,
    const int* __restrict__ colsrc, const float* __restrict__ bias,
    unsigned short* __restrict__ outp, int N)
{
  int wid  = threadIdx.x >> 6;
  int lane = threadIdx.x & 63;
  int n = blockIdx.x * 4 + wid;
  if (n >= N) return;
  const int half = lane >> 5;                     // 0: even edges, 1: odd edges
  const int fl   = lane & 31;                     // 8 feats at fl*8
  const int head = (H == 2) ? (fl >> 4) : 0;      // feature col >= 128 -> head 1

  int beg = rowptr[n], end = rowptr[n + 1];

  float ad0 = adst[(size_t)n * H + 0];
  float ad1 = (H == 2) ? adst[(size_t)n * 2 + 1] : 0.f;
  float m0 = lrelu(asrc[(size_t)n * H + 0] + ad0, 0.2f);       // self-loop logit
  float m1 = (H == 2) ? lrelu(asrc[(size_t)n * 2 + 1] + ad1, 0.2f) : 0.f;
  float s0 = 1.f, s1 = 1.f;                        // exp(self - m) = 1

  float acc[8];
  {
    s16x8 hv = *(const s16x8*)&hin[(size_t)n * 256 + fl * 8];
    #pragma unroll
    for (int k = 0; k < 8; ++k)
      acc[k] = (half == 0) ? bf2f((unsigned short)hv[k]) : 0.f;
  }

  for (int cbeg = beg; cbeg < end; cbeg += 64) {
    int cnt = end - cbeg; if (cnt > 64) cnt = 64;
    int src_i = 0;
    float e0 = -1e30f, e1 = -1e30f;
    if (lane < cnt) {
      src_i = colsrc[cbeg + lane];
      if (H == 2) {
        float2 av = *(const float2*)&asrc[(size_t)src_i * 2];
        e0 = lrelu(av.x + ad0, 0.2f);
        e1 = lrelu(av.y + ad1, 0.2f);
      } else {
        e0 = lrelu(asrc[src_i] + ad0, 0.2f);
      }
    }
    // chunk max
    float c0 = e0, c1 = e1;
    #pragma unroll
    for (int off = 32; off >= 1; off >>= 1) {
      c0 = fmaxf(c0, __shfl_xor(c0, off, 64));
      if (H == 2) c1 = fmaxf(c1, __shfl_xor(c1, off, 64));
    }
    float nm0 = fmaxf(m0, c0);
    float r0 = __expf(m0 - nm0); m0 = nm0;
    float r1 = 1.f;
    if (H == 2) { float nm1 = fmaxf(m1, c1); r1 = __expf(m1 - nm1); m1 = nm1; }
    s0 *= r0; if (H == 2) s1 *= r1;
    float rh = (H == 2 && head) ? r1 : r0;
    #pragma unroll
    for (int k = 0; k < 8; ++k) acc[k] *= rh;
    // per-edge p (0 for invalid lanes)
    float p0 = (lane < cnt) ? __expf(e0 - m0) : 0.f;
    float p1 = (H == 2 && lane < cnt) ? __expf(e1 - m1) : 0.f;
    float t0 = p0, t1 = p1;
    #pragma unroll
    for (int off = 32; off >= 1; off >>= 1) {
      t0 += __shfl_xor(t0, off, 64);
      if (H == 2) t1 += __shfl_xor(t1, off, 64);
    }
    s0 += t0; if (H == 2) s1 += t1;

    // gather: 2 edges per step (half 0/1), unrolled x2
    int npair = (cnt + 1) >> 1;
    int pi = 0;
    for (; pi + 2 <= npair; pi += 2) {
      int ia = pi * 2, ib = pi * 2 + 2;
      int sa0 = __shfl(src_i, ia, 64),     sa1 = __shfl(src_i, ia + 1, 64);
      int sb0 = __shfl(src_i, ib, 64),     sb1 = __shfl(src_i, ib + 1, 64);
      float qa00 = __shfl(p0, ia, 64),     qa01 = __shfl(p0, ia + 1, 64);
      float qb00 = __shfl(p0, ib, 64),     qb01 = __shfl(p0, ib + 1, 64);
      float wA, wB;
      if (H == 2) {
        float qa10 = __shfl(p1, ia, 64), qa11 = __shfl(p1, ia + 1, 64);
        float qb10 = __shfl(p1, ib, 64), qb11 = __shfl(p1, ib + 1, 64);
        wA = head ? (half ? qa11 : qa10) : (half ? qa01 : qa00);
        wB = head ? (half ? qb11 : qb10) : (half ? qb01 : qb00);
      } else {
        wA = half ? qa01 : qa00;
        wB = half ? qb01 : qb00;
      }
      int sjA = half ? sa1 : sa0;
      int sjB = half ? sb1 : sb0;
      s16x8 vA = *(const s16x8*)&hin[(size_t)sjA * 256 + fl * 8];
      s16x8 vB = *(const s16x8*)&hin[(size_t)sjB * 256 + fl * 8];
      #pragma unroll
      for (int k = 0; k < 8; ++k) acc[k] = fmaf(bf2f((unsigned short)vA[k]), wA, acc[k]);
      #pragma unroll
      for (int k = 0; k < 8; ++k) acc[k] = fmaf(bf2f((unsigned short)vB[k]), wB, acc[k]);
    }
    for (; pi < npair; ++pi) {
      int ia = pi * 2;
      int sa0 = __shfl(src_i, ia, 64), sa1 = __shfl(src_i, ia + 1, 64);
      float qa00 = __shfl(p0, ia, 64), qa01 = __shfl(p0, ia + 1, 64);
      float wA;
      if (H == 2) {
        float qa10 = __shfl(p1, ia, 64), qa11 = __shfl(p1, ia + 1, 64);
        wA = head ? (half ? qa11 : qa10) : (half ? qa01 : qa00);
      } else {
        wA = half ? qa01 : qa00;
      }
      int sjA = half ? sa1 : sa0;
      s16x8 vA = *(const s16x8*)&hin[(size_t)sjA * 256 + fl * 8];
      #pragma unroll
      for (int k = 0; k < 8; ++k) acc[k] = fmaf(bf2f((unsigned short)vA[k]), wA, acc[k]);
    }
  }

  float sh = (H == 2 && head) ? s1 : s0;
  float inv = 1.0f / sh;
  #pragma unroll
  for (int k = 0; k < 8; ++k) acc[k] += __shfl_xor(acc[k], 32, 64);
  if (half == 0) {
    float bv[8];
    *(float4*)&bv[0] = *(const float4*)&bias[fl * 8];
    *(float4*)&bv[4] = *(const float4*)&bias[fl * 8 + 4];
    s16x8 o;
    #pragma unroll
    for (int k = 0; k < 8; ++k) {
      float v = acc[k] * inv + bv[k];
      if (OUT_LRELU) v = lrelu(v, 0.01f);
      o[k] = (short)f2bf(v);
    }
    *(s16x8*)&outp[(size_t)n * 256 + fl * 8] = o;
  }
}

// ======================== mu norms ========================
__global__ __launch_bounds__(64) void munorm_kernel(const float* __restrict__ mu,
                                                    float* __restrict__ norm_mu) {
  int lane = threadIdx.x;
  for (int k = 0; k < 8; ++k) {
    float v0 = mu[k * 128 + lane];
    float v1 = mu[k * 128 + 64 + lane];
    float s = v0 * v0 + v1 * v1;
    #pragma unroll
    for (int off = 1; off < 64; off <<= 1) s += __shfl_xor(s, off, 64);
    if (lane == 0) norm_mu[k] = sqrtf(s);
  }
}

// ======================== launch ========================
extern "C" void kernel_launch(void* const* d_in, const int* in_sizes, int n_in,
                              void* d_out, int out_size, void* d_ws, size_t ws_size,
                              hipStream_t stream) {
  const float* x      = (const float*)d_in[0];
  const int*   ei     = (const int*)  d_in[1];
  const float* W1     = (const float*)d_in[2];
  const float* a_src1 = (const float*)d_in[3];
  const float* a_dst1 = (const float*)d_in[4];
  const float* b1     = (const float*)d_in[5];
  const float* W2     = (const float*)d_in[6];
  const float* a_src2 = (const float*)d_in[7];
  const float* a_dst2 = (const float*)d_in[8];
  const float* b2     = (const float*)d_in[9];
  const float* g      = (const float*)d_in[10];
  const float* mu     = (const float*)d_in[11];

  const int N  = in_sizes[0] / 256;            // 50000
  const int E  = in_sizes[1] / 2;              // 800000
  const int Mp = ((N + 127) / 128) * 128;      // 50048
  const int* src = ei;
  const int* dst = ei + E;

  // ---- workspace layout ----
  unsigned short* us = (unsigned short*)d_ws;
  size_t off = 0;
  unsigned short* xb  = us + off; off += (size_t)Mp * 256;   // x bf16 (reused as out2b)
  unsigned short* h1b = us + off; off += (size_t)Mp * 256;
  unsigned short* o1b = us + off; off += (size_t)Mp * 256;
  unsigned short* h2b = us + off; off += (size_t)Mp * 256;
  unsigned short* o2b = xb;                                  // alias: xb dead after gemm1
  float* f = (float*)(us + off);
  size_t fo = 0;
  float* asrc1 = f + fo; fo += (size_t)N * 2;
  float* adst1 = f + fo; fo += (size_t)N * 2;
  float* asrc2 = f + fo; fo += N;
  float* adst2 = f + fo; fo += N;
  float* nmu   = f + fo; fo += 8;
  int* deg    = (int*)(f + fo);
  int* rowptr = deg + N;
  int* cursor = rowptr + N + 1;
  int* colsrc = cursor + N;
  unsigned short* w1b = (unsigned short*)(colsrc + E);
  unsigned short* w2b = w1b + 256 * 256;
  unsigned short* gTb = w2b + 256 * 256;

  // ---- CSR build ----
  hipMemsetAsync(deg, 0, (size_t)N * sizeof(int), stream);
  hipMemsetAsync(asrc2, 0, (size_t)N * 2 * sizeof(float), stream);  // asrc2+adst2 contiguous
  deg_kernel<<<(E + 255) / 256, 256, 0, stream>>>(dst, deg, E);
  scan_kernel<<<1, 1024, 0, stream>>>(deg, rowptr, N);
  hipMemcpyAsync(cursor, rowptr, (size_t)N * sizeof(int), hipMemcpyDeviceToDevice, stream);
  fill_kernel<<<(E + 255) / 256, 256, 0, stream>>>(src, dst, cursor, colsrc, E);

  // ---- conversions ----
  cvt_rows_kernel<<<Mp / 4, 256, 0, stream>>>(x, xb, N, Mp);
  cvt_rows_kernel<<<64, 256, 0, stream>>>(W1, w1b, 256, 256);
  cvt_rows_kernel<<<64, 256, 0, stream>>>(W2, w2b, 256, 256);
  cvt_gT_kernel<<<1024, 256, 0, stream>>>(g, gTb);
  munorm_kernel<<<1, 64, 0, stream>>>(mu, nmu);

  const int gm = Mp / 128;   // 391

  // ---- layer 1 (alpha fused into GEMM epilogue: blockIdx.y == head) ----
  gemm_bf16<0, 2><<<dim3(gm, 2), 256, 0, stream>>>(xb, w1b, h1b,
      a_src1, a_dst1, asrc1, adst1, nullptr, nullptr, nullptr, N);
  agg_kernel<2, true><<<(N + 3) / 4, 256, 0, stream>>>(h1b, asrc1, adst1, rowptr, colsrc, b1, o1b, N);

  // ---- layer 2 (alpha partials via atomicAdd into zeroed asrc2/adst2) ----
  gemm_bf16<0, 1><<<dim3(gm, 2), 256, 0, stream>>>(o1b, w2b, h2b,
      a_src2, a_dst2, asrc2, adst2, nullptr, nullptr, nullptr, N);
  agg_kernel<1, false><<<(N + 3) / 4, 256, 0, stream>>>(h2b, asrc2, adst2, rowptr, colsrc, b2, o2b, N);

  // ---- projection + fused cosine ----
  gemm_bf16<1, 0><<<dim3(gm, 8), 256, 0, stream>>>(o2b, gTb, nullptr,
      nullptr, nullptr, nullptr, nullptr, mu, nmu, (float*)d_out, N);
}

// Round 4
// 413.666 us; speedup vs baseline: 2.7303x; 1.2142x over previous
//
#include <hip/hip_runtime.h>
#include <math.h>

typedef short s16x8 __attribute__((ext_vector_type(8)));
typedef float f32x4 __attribute__((ext_vector_type(4)));

__device__ __forceinline__ float lrelu(float x, float s) { return x > 0.0f ? x : s * x; }

// RNE f32 -> bf16 (bit-level)
__device__ __forceinline__ unsigned short f2bf(float f) {
  unsigned int u = __float_as_uint(f);
  u = (u + 0x7FFFu + ((u >> 16) & 1u)) >> 16;
  return (unsigned short)u;
}
__device__ __forceinline__ float bf2f(unsigned short h) {
  return __uint_as_float(((unsigned int)h) << 16);
}

// async global->LDS, 16B per lane; LDS dest is wave-uniform base + lane*16
__device__ __forceinline__ void gload_lds16(void* lds, const void* g) {
  __builtin_amdgcn_global_load_lds(
      (const __attribute__((address_space(1))) unsigned int*)g,
      (__attribute__((address_space(3))) unsigned int*)lds, 16, 0, 0);
}

// ======================== CSR build ========================
__global__ void deg_kernel(const int* __restrict__ dst, int* __restrict__ deg, int E) {
  int e = blockIdx.x * blockDim.x + threadIdx.x;
  if (e < E) atomicAdd(&deg[dst[e]], 1);
}

// --- device-wide exclusive scan of deg[N], 3 tiny kernels ---
__global__ __launch_bounds__(256) void bsum_kernel(const int* __restrict__ deg,
                                                   int* __restrict__ bsum, int N) {
  int t = blockIdx.x * 256 + threadIdx.x;
  int v = (t < N) ? deg[t] : 0;
  #pragma unroll
  for (int off = 1; off < 64; off <<= 1) v += __shfl_xor(v, off, 64);
  __shared__ int ws[4];
  if ((threadIdx.x & 63) == 0) ws[threadIdx.x >> 6] = v;
  __syncthreads();
  if (threadIdx.x == 0) bsum[blockIdx.x] = ws[0] + ws[1] + ws[2] + ws[3];
}

__global__ __launch_bounds__(256) void bscan_kernel(const int* __restrict__ bsum,
                                                    int* __restrict__ boff, int nb,
                                                    int* __restrict__ rowptr_total) {
  __shared__ int s[256];
  int t = threadIdx.x;
  int v = (t < nb) ? bsum[t] : 0;
  s[t] = v;
  __syncthreads();
  for (int off = 1; off < 256; off <<= 1) {
    int u = (t >= off) ? s[t - off] : 0;
    __syncthreads();
    s[t] += u;
    __syncthreads();
  }
  if (t < nb) boff[t] = s[t] - v;               // exclusive block offset
  if (t == nb - 1) *rowptr_total = s[t];        // rowptr[N] = E total
}

__global__ __launch_bounds__(256) void bwrite_kernel(const int* __restrict__ deg,
                                                     const int* __restrict__ boff,
                                                     int* __restrict__ rowptr,
                                                     int* __restrict__ cursor, int N) {
  __shared__ int s[256];
  int t = blockIdx.x * 256 + threadIdx.x;
  int v = (t < N) ? deg[t] : 0;
  s[threadIdx.x] = v;
  __syncthreads();
  for (int off = 1; off < 256; off <<= 1) {
    int u = (threadIdx.x >= off) ? s[threadIdx.x - off] : 0;
    __syncthreads();
    s[threadIdx.x] += u;
    __syncthreads();
  }
  if (t < N) {
    int ex = boff[blockIdx.x] + s[threadIdx.x] - v;   // exclusive prefix
    rowptr[t] = ex;
    cursor[t] = ex;
  }
}

__global__ void fill_kernel(const int* __restrict__ src, const int* __restrict__ dst,
                            int* __restrict__ cursor, int* __restrict__ colsrc, int E) {
  int e = blockIdx.x * blockDim.x + threadIdx.x;
  if (e < E) {
    int d = dst[e];
    int pos = atomicAdd(&cursor[d], 1);
    colsrc[pos] = src[e];
  }
}

// ======================== f32 -> bf16 conversions ========================
__global__ void cvt_rows_kernel(const float* __restrict__ src, unsigned short* __restrict__ dst,
                                int nrows, int prows) {
  int t = blockIdx.x * blockDim.x + threadIdx.x;
  int row = t >> 6;
  int c = (t & 63) * 4;
  if (row >= prows) return;
  float4 v = make_float4(0.f, 0.f, 0.f, 0.f);
  if (row < nrows) v = *(const float4*)&src[(size_t)row * 256 + c];
  ushort4 o;
  o.x = f2bf(v.x); o.y = f2bf(v.y); o.z = f2bf(v.z); o.w = f2bf(v.w);
  *(ushort4*)&dst[(size_t)row * 256 + c] = o;
}

__global__ void cvt_gT_kernel(const float* __restrict__ g, unsigned short* __restrict__ gT) {
  int idx = blockIdx.x * blockDim.x + threadIdx.x;  // 0..262143
  int k = idx >> 10, n = idx & 1023;
  gT[(size_t)n * 256 + k] = f2bf(g[idx]);
}

// ======================== bf16 MFMA GEMM, 128x128 tile, BK=64 ========================
// A: [Mp][256] bf16. B: [Ntot][256] bf16 (row = out col). 4 waves; wave w owns rows
// w*32..+31 x 128 cols. LDS 16B-chunk XOR-swizzled via pre-swizzled global src (rule 21).
// EPI=0: store C bf16 [Mp][256]; AH>0: fused a_src/a_dst dot products.
//   AH==2: blockIdx.y == head, direct store. AH==1: atomicAdd partials (zeroed before).
// EPI=1: fused cosine epilogue (block col-tile == K-chunk of 128).
template<int EPI, int AH>
__global__ __launch_bounds__(256, 2) void gemm_bf16(
    const unsigned short* __restrict__ A, const unsigned short* __restrict__ B,
    unsigned short* __restrict__ Cb,
    const float* __restrict__ avs, const float* __restrict__ avd,
    float* __restrict__ asrcO, float* __restrict__ adstO,
    const float* __restrict__ mu, const float* __restrict__ nmu,
    float* __restrict__ outcos, int M)
{
  __shared__ unsigned short As[128 * 64];
  __shared__ unsigned short Bs[128 * 64];
  const int t = threadIdx.x;
  const int w = t >> 6;
  const int l = t & 63;
  const int m0 = blockIdx.x * 128;
  const int n0 = blockIdx.y * 128;

  f32x4 acc[2][8];
  #pragma unroll
  for (int i = 0; i < 2; ++i)
    #pragma unroll
    for (int j = 0; j < 8; ++j) acc[i][j] = (f32x4){0.f, 0.f, 0.f, 0.f};

  const unsigned char* Ab = (const unsigned char*)A;
  const unsigned char* Bb = (const unsigned char*)B;
  unsigned char* AsB = (unsigned char*)As;
  unsigned char* BsB = (unsigned char*)Bs;

  const int srow = l >> 3;               // 0..7: row within 8-row segment
  const int gchk = (l & 7) ^ srow;       // pre-swizzled global 16B-chunk index

  for (int kb = 0; kb < 256; kb += 64) {
    #pragma unroll
    for (int i = 0; i < 4; ++i) {
      int seg = w * 4 + i;               // 16 segments of 8 rows each
      int row = seg * 8 + srow;          // local row 0..127
      gload_lds16(AsB + seg * 1024,
                  Ab + (size_t)(m0 + row) * 512 + kb * 2 + gchk * 16);
      gload_lds16(BsB + seg * 1024,
                  Bb + (size_t)(n0 + row) * 512 + kb * 2 + gchk * 16);
    }
    asm volatile("s_waitcnt vmcnt(0)" ::: "memory");
    __syncthreads();

    const int rl = l & 15;
    const int kc = l >> 4;               // 0..3
    #pragma unroll
    for (int ks = 0; ks < 2; ++ks) {
      s16x8 af[2], bfr[8];
      #pragma unroll
      for (int mf = 0; mf < 2; ++mf) {
        int r = w * 32 + mf * 16 + rl;
        int slot = (ks * 4 + kc) ^ (r & 7);
        af[mf] = *(const s16x8*)&As[r * 64 + slot * 8];
      }
      #pragma unroll
      for (int nf = 0; nf < 8; ++nf) {
        int r = nf * 16 + rl;
        int slot = (ks * 4 + kc) ^ (r & 7);
        bfr[nf] = *(const s16x8*)&Bs[r * 64 + slot * 8];
      }
      #pragma unroll
      for (int mf = 0; mf < 2; ++mf)
        #pragma unroll
        for (int nf = 0; nf < 8; ++nf)
          acc[mf][nf] = __builtin_amdgcn_mfma_f32_16x16x32_bf16(af[mf], bfr[nf], acc[mf][nf], 0, 0, 0);
    }
    __syncthreads();
  }

  if (EPI == 0) {
    // C/D layout: col = lane&15, row = (lane>>4)*4 + reg  [m89/m91 verified]
    #pragma unroll
    for (int mf = 0; mf < 2; ++mf)
      #pragma unroll
      for (int nf = 0; nf < 8; ++nf)
        #pragma unroll
        for (int j = 0; j < 4; ++j) {
          int r = m0 + w * 32 + mf * 16 + (l >> 4) * 4 + j;
          int c = n0 + nf * 16 + (l & 15);
          Cb[(size_t)r * 256 + c] = f2bf(acc[mf][nf][j]);
        }
    if (AH > 0) {
      float avS[8], avD[8];
      #pragma unroll
      for (int nf = 0; nf < 8; ++nf) {
        avS[nf] = avs[n0 + nf * 16 + (l & 15)];
        avD[nf] = avd[n0 + nf * 16 + (l & 15)];
      }
      #pragma unroll
      for (int mf = 0; mf < 2; ++mf)
        #pragma unroll
        for (int j = 0; j < 4; ++j) {
          float ds = 0.f, dd = 0.f;
          #pragma unroll
          for (int nf = 0; nf < 8; ++nf) {
            float o = acc[mf][nf][j];
            ds = fmaf(o, avS[nf], ds);
            dd = fmaf(o, avD[nf], dd);
          }
          #pragma unroll
          for (int off = 1; off < 16; off <<= 1) {
            ds += __shfl_xor(ds, off, 64);
            dd += __shfl_xor(dd, off, 64);
          }
          if ((l & 15) == 0) {
            int r = m0 + w * 32 + mf * 16 + (l >> 4) * 4 + j;
            if (r < M) {
              if (AH == 2) {
                asrcO[(size_t)r * 2 + blockIdx.y] = ds;
                adstO[(size_t)r * 2 + blockIdx.y] = dd;
              } else {
                atomicAdd(&asrcO[r], ds);
                atomicAdd(&adstO[r], dd);
              }
            }
          }
        }
    }
  } else {
    const int kchunk = blockIdx.y;       // 0..7
    float nm = nmu[kchunk];
    float mv[8];
    #pragma unroll
    for (int nf = 0; nf < 8; ++nf) mv[nf] = mu[kchunk * 128 + nf * 16 + (l & 15)];
    #pragma unroll
    for (int mf = 0; mf < 2; ++mf)
      #pragma unroll
      for (int j = 0; j < 4; ++j) {
        float num = 0.f, ss = 0.f;
        #pragma unroll
        for (int nf = 0; nf < 8; ++nf) {
          float o = acc[mf][nf][j];
          num = fmaf(o, mv[nf], num);
          ss  = fmaf(o, o, ss);
        }
        #pragma unroll
        for (int off = 1; off < 16; off <<= 1) {
          num += __shfl_xor(num, off, 64);
          ss  += __shfl_xor(ss, off, 64);
        }
        if ((l & 15) == 0) {
          int r = m0 + w * 32 + mf * 16 + (l >> 4) * 4 + j;
          if (r < M) outcos[(size_t)r * 8 + kchunk] = num / fmaxf(sqrtf(ss) * nm, 1e-8f);
        }
      }
  }
}

// ======================== GAT aggregation ========================
// One wave per node. Lane-parallel chunked online softmax (64 edges/chunk),
// then gather with 16B/lane (short8), 32 lanes per row => 2 edges per wave-step,
// unrolled x2 (4 row-gathers in flight). Halves merged at the end.
template<int H, bool OUT_LRELU>
__global__ __launch_bounds__(256) void agg_kernel(
    const unsigned short* __restrict__ hin, const float* __restrict__ asrc,
    const float* __restrict__ adst, const int* __restrict__ rowptr,
    const int* __restrict__ colsrc, const float* __restrict__ bias,
    unsigned short* __restrict__ outp, int N)
{
  int wid  = threadIdx.x >> 6;
  int lane = threadIdx.x & 63;
  int n = blockIdx.x * 4 + wid;
  if (n >= N) return;
  const int half = lane >> 5;                     // 0: even edges, 1: odd edges
  const int fl   = lane & 31;                     // 8 feats at fl*8
  const int head = (H == 2) ? (fl >> 4) : 0;      // feature col >= 128 -> head 1

  int beg = rowptr[n], end = rowptr[n + 1];

  float ad0 = adst[(size_t)n * H + 0];
  float ad1 = (H == 2) ? adst[(size_t)n * 2 + 1] : 0.f;
  float m0 = lrelu(asrc[(size_t)n * H + 0] + ad0, 0.2f);       // self-loop logit
  float m1 = (H == 2) ? lrelu(asrc[(size_t)n * 2 + 1] + ad1, 0.2f) : 0.f;
  float s0 = 1.f, s1 = 1.f;                        // exp(self - m) = 1

  float acc[8];
  {
    s16x8 hv = *(const s16x8*)&hin[(size_t)n * 256 + fl * 8];
    #pragma unroll
    for (int k = 0; k < 8; ++k)
      acc[k] = (half == 0) ? bf2f((unsigned short)hv[k]) : 0.f;
  }

  for (int cbeg = beg; cbeg < end; cbeg += 64) {
    int cnt = end - cbeg; if (cnt > 64) cnt = 64;
    int src_i = 0;
    float e0 = -1e30f, e1 = -1e30f;
    if (lane < cnt) {
      src_i = colsrc[cbeg + lane];
      if (H == 2) {
        float2 av = *(const float2*)&asrc[(size_t)src_i * 2];
        e0 = lrelu(av.x + ad0, 0.2f);
        e1 = lrelu(av.y + ad1, 0.2f);
      } else {
        e0 = lrelu(asrc[src_i] + ad0, 0.2f);
      }
    }
    // chunk max
    float c0 = e0, c1 = e1;
    #pragma unroll
    for (int off = 32; off >= 1; off >>= 1) {
      c0 = fmaxf(c0, __shfl_xor(c0, off, 64));
      if (H == 2) c1 = fmaxf(c1, __shfl_xor(c1, off, 64));
    }
    float nm0 = fmaxf(m0, c0);
    float r0 = __expf(m0 - nm0); m0 = nm0;
    float r1 = 1.f;
    if (H == 2) { float nm1 = fmaxf(m1, c1); r1 = __expf(m1 - nm1); m1 = nm1; }
    s0 *= r0; if (H == 2) s1 *= r1;
    float rh = (H == 2 && head) ? r1 : r0;
    #pragma unroll
    for (int k = 0; k < 8; ++k) acc[k] *= rh;
    // per-edge p (0 for invalid lanes)
    float p0 = (lane < cnt) ? __expf(e0 - m0) : 0.f;
    float p1 = (H == 2 && lane < cnt) ? __expf(e1 - m1) : 0.f;
    float t0 = p0, t1 = p1;
    #pragma unroll
    for (int off = 32; off >= 1; off >>= 1) {
      t0 += __shfl_xor(t0, off, 64);
      if (H == 2) t1 += __shfl_xor(t1, off, 64);
    }
    s0 += t0; if (H == 2) s1 += t1;

    // gather: 2 edges per step (half 0/1), unrolled x2
    int npair = (cnt + 1) >> 1;
    int pi = 0;
    for (; pi + 2 <= npair; pi += 2) {
      int ia = pi * 2, ib = pi * 2 + 2;
      int sa0 = __shfl(src_i, ia, 64),     sa1 = __shfl(src_i, ia + 1, 64);
      int sb0 = __shfl(src_i, ib, 64),     sb1 = __shfl(src_i, ib + 1, 64);
      float qa00 = __shfl(p0, ia, 64),     qa01 = __shfl(p0, ia + 1, 64);
      float qb00 = __shfl(p0, ib, 64),     qb01 = __shfl(p0, ib + 1, 64);
      float wA, wB;
      if (H == 2) {
        float qa10 = __shfl(p1, ia, 64), qa11 = __shfl(p1, ia + 1, 64);
        float qb10 = __shfl(p1, ib, 64), qb11 = __shfl(p1, ib + 1, 64);
        wA = head ? (half ? qa11 : qa10) : (half ? qa01 : qa00);
        wB = head ? (half ? qb11 : qb10) : (half ? qb01 : qb00);
      } else {
        wA = half ? qa01 : qa00;
        wB = half ? qb01 : qb00;
      }
      int sjA = half ? sa1 : sa0;
      int sjB = half ? sb1 : sb0;
      s16x8 vA = *(const s16x8*)&hin[(size_t)sjA * 256 + fl * 8];
      s16x8 vB = *(const s16x8*)&hin[(size_t)sjB * 256 + fl * 8];
      #pragma unroll
      for (int k = 0; k < 8; ++k) acc[k] = fmaf(bf2f((unsigned short)vA[k]), wA, acc[k]);
      #pragma unroll
      for (int k = 0; k < 8; ++k) acc[k] = fmaf(bf2f((unsigned short)vB[k]), wB, acc[k]);
    }
    for (; pi < npair; ++pi) {
      int ia = pi * 2;
      int sa0 = __shfl(src_i, ia, 64), sa1 = __shfl(src_i, ia + 1, 64);
      float qa00 = __shfl(p0, ia, 64), qa01 = __shfl(p0, ia + 1, 64);
      float wA;
      if (H == 2) {
        float qa10 = __shfl(p1, ia, 64), qa11 = __shfl(p1, ia + 1, 64);
        wA = head ? (half ? qa11 : qa10) : (half ? qa01 : qa00);
      } else {
        wA = half ? qa01 : qa00;
      }
      int sjA = half ? sa1 : sa0;
      s16x8 vA = *(const s16x8*)&hin[(size_t)sjA * 256 + fl * 8];
      #pragma unroll
      for (int k = 0; k < 8; ++k) acc[k] = fmaf(bf2f((unsigned short)vA[k]), wA, acc[k]);
    }
  }

  float sh = (H == 2 && head) ? s1 : s0;
  float inv = 1.0f / sh;
  #pragma unroll
  for (int k = 0; k < 8; ++k) acc[k] += __shfl_xor(acc[k], 32, 64);
  if (half == 0) {
    float bv[8];
    *(float4*)&bv[0] = *(const float4*)&bias[fl * 8];
    *(float4*)&bv[4] = *(const float4*)&bias[fl * 8 + 4];
    s16x8 o;
    #pragma unroll
    for (int k = 0; k < 8; ++k) {
      float v = acc[k] * inv + bv[k];
      if (OUT_LRELU) v = lrelu(v, 0.01f);
      o[k] = (short)f2bf(v);
    }
    *(s16x8*)&outp[(size_t)n * 256 + fl * 8] = o;
  }
}

// ======================== mu norms ========================
__global__ __launch_bounds__(64) void munorm_kernel(const float* __restrict__ mu,
                                                    float* __restrict__ norm_mu) {
  int lane = threadIdx.x;
  for (int k = 0; k < 8; ++k) {
    float v0 = mu[k * 128 + lane];
    float v1 = mu[k * 128 + 64 + lane];
    float s = v0 * v0 + v1 * v1;
    #pragma unroll
    for (int off = 1; off < 64; off <<= 1) s += __shfl_xor(s, off, 64);
    if (lane == 0) norm_mu[k] = sqrtf(s);
  }
}

// ======================== launch ========================
extern "C" void kernel_launch(void* const* d_in, const int* in_sizes, int n_in,
                              void* d_out, int out_size, void* d_ws, size_t ws_size,
                              hipStream_t stream) {
  const float* x      = (const float*)d_in[0];
  const int*   ei     = (const int*)  d_in[1];
  const float* W1     = (const float*)d_in[2];
  const float* a_src1 = (const float*)d_in[3];
  const float* a_dst1 = (const float*)d_in[4];
  const float* b1     = (const float*)d_in[5];
  const float* W2     = (const float*)d_in[6];
  const float* a_src2 = (const float*)d_in[7];
  const float* a_dst2 = (const float*)d_in[8];
  const float* b2     = (const float*)d_in[9];
  const float* g      = (const float*)d_in[10];
  const float* mu     = (const float*)d_in[11];

  const int N  = in_sizes[0] / 256;            // 50000
  const int E  = in_sizes[1] / 2;              // 800000
  const int Mp = ((N + 127) / 128) * 128;      // 50048
  const int nb = (N + 255) / 256;              // 196 scan blocks
  const int* src = ei;
  const int* dst = ei + E;

  // ---- workspace layout ----
  unsigned short* us = (unsigned short*)d_ws;
  size_t off = 0;
  unsigned short* xb  = us + off; off += (size_t)Mp * 256;   // x bf16 (reused as out2b)
  unsigned short* h1b = us + off; off += (size_t)Mp * 256;
  unsigned short* o1b = us + off; off += (size_t)Mp * 256;
  unsigned short* h2b = us + off; off += (size_t)Mp * 256;
  unsigned short* o2b = xb;                                  // alias: xb dead after gemm1
  float* f = (float*)(us + off);
  size_t fo = 0;
  float* asrc1 = f + fo; fo += (size_t)N * 2;
  float* adst1 = f + fo; fo += (size_t)N * 2;
  float* asrc2 = f + fo; fo += N;
  float* adst2 = f + fo; fo += N;
  float* nmu   = f + fo; fo += 8;
  int* deg    = (int*)(f + fo);
  int* rowptr = deg + N;
  int* cursor = rowptr + N + 1;
  int* colsrc = cursor + N;
  int* bsum   = colsrc + E;          // nb
  int* boff   = bsum + 256;          // nb
  unsigned short* w1b = (unsigned short*)(boff + 256);
  unsigned short* w2b = w1b + 256 * 256;
  unsigned short* gTb = w2b + 256 * 256;

  // ---- CSR build ----
  hipMemsetAsync(deg, 0, (size_t)N * sizeof(int), stream);
  hipMemsetAsync(asrc2, 0, (size_t)N * 2 * sizeof(float), stream);  // asrc2+adst2 contiguous
  deg_kernel<<<(E + 255) / 256, 256, 0, stream>>>(dst, deg, E);
  bsum_kernel<<<nb, 256, 0, stream>>>(deg, bsum, N);
  bscan_kernel<<<1, 256, 0, stream>>>(bsum, boff, nb, rowptr + N);
  bwrite_kernel<<<nb, 256, 0, stream>>>(deg, boff, rowptr, cursor, N);
  fill_kernel<<<(E + 255) / 256, 256, 0, stream>>>(src, dst, cursor, colsrc, E);

  // ---- conversions ----
  cvt_rows_kernel<<<Mp / 4, 256, 0, stream>>>(x, xb, N, Mp);
  cvt_rows_kernel<<<64, 256, 0, stream>>>(W1, w1b, 256, 256);
  cvt_rows_kernel<<<64, 256, 0, stream>>>(W2, w2b, 256, 256);
  cvt_gT_kernel<<<1024, 256, 0, stream>>>(g, gTb);
  munorm_kernel<<<1, 64, 0, stream>>>(mu, nmu);

  const int gm = Mp / 128;   // 391

  // ---- layer 1 (alpha fused into GEMM epilogue: blockIdx.y == head) ----
  gemm_bf16<0, 2><<<dim3(gm, 2), 256, 0, stream>>>(xb, w1b, h1b,
      a_src1, a_dst1, asrc1, adst1, nullptr, nullptr, nullptr, N);
  agg_kernel<2, true><<<(N + 3) / 4, 256, 0, stream>>>(h1b, asrc1, adst1, rowptr, colsrc, b1, o1b, N);

  // ---- layer 2 (alpha partials via atomicAdd into zeroed asrc2/adst2) ----
  gemm_bf16<0, 1><<<dim3(gm, 2), 256, 0, stream>>>(o1b, w2b, h2b,
      a_src2, a_dst2, asrc2, adst2, nullptr, nullptr, nullptr, N);
  agg_kernel<1, false><<<(N + 3) / 4, 256, 0, stream>>>(h2b, asrc2, adst2, rowptr, colsrc, b2, o2b, N);

  // ---- projection + fused cosine ----
  gemm_bf16<1, 0><<<dim3(gm, 8), 256, 0, stream>>>(o2b, gTb, nullptr,
      nullptr, nullptr, nullptr, nullptr, mu, nmu, (float*)d_out, N);
}